// Round 2
// baseline (1662.705 us; speedup 1.0000x reference)
//
#include <hip/hip_runtime.h>
#include <math.h>

#define N_NODES 50000
#define N_EDGES 800000
#define DIN 256
#define DHID 128
#define DOUT 64
// Padded CSR row stride. In-degree ~ Poisson(16); P(deg > 64) ~ 1e-19 -> safe.
#define CSTRIDE 64
#define ZROW N_NODES            // sentinel row (kept zero)
#define HBLOCKS 256
#define HCHUNK (N_EDGES / HBLOCKS)     // 3125
#define HWORDS (N_NODES / 4)           // 12500
#define SLICE ((size_t)(N_NODES + 1) * 16)
#define NGROUPS (N_NODES / 4)          // 12500
#define P2BLOCKS 196                   // hpre/dscatter blocks (12500/64 word-cols)

// Persistent kernel geometry: 2048 blocks = 8 blocks/CU x 256 CUs, exactly
// co-resident at <=64 VGPR (launch_bounds(256,8)) + 2 KB LDS -> a software
// grid barrier cannot starve (all blocks resident simultaneously).
#define PBLOCKS 2048
#define PWAVES_Q 2048                  // waves per q-slice (512 blocks x 4 waves)

// ---------------- fat setup kernel: sentinel-fill csr, 2 histograms, weight folds ----
#define SB_SENT 3125
#define SB_HS (SB_SENT + HBLOCKS)       // 3381
#define SB_HD (SB_HS + HBLOCKS)         // 3637
#define SB_TOT (SB_HD + 66)             // 3703

__global__ void k_setup(const int* __restrict__ src, const int* __restrict__ dst,
                        unsigned int* __restrict__ pS, unsigned int* __restrict__ pD,
                        unsigned int* __restrict__ csr32,
                        const float* __restrict__ W1, const float* __restrict__ b1,
                        const float* __restrict__ W3,
                        float* __restrict__ W13, float* __restrict__ bb,
                        float* __restrict__ Y0, float* __restrict__ Y1,
                        unsigned int* __restrict__ bar) {
    __shared__ unsigned int h[HWORDS];
    int bx = blockIdx.x, t = threadIdx.x;
    if (bx < SB_SENT) {
        // pre-fill every csr slot with the sentinel (k_fill overwrites [0,deg))
        unsigned int v = (unsigned int)ZROW | ((unsigned int)ZROW << 16);
        uint2 o; o.x = v; o.y = v;
        ((uint2*)csr32)[bx * 256 + t] = o;
        return;
    }
    if (bx < SB_HD) {
        // byte-packed LDS-privatized histogram (4 bins per u32); per-block
        // per-node counts <= total degree (<=64) << 255 -> no byte carry.
        const int* idx = (bx < SB_HS) ? src : dst;
        unsigned int* outp = (bx < SB_HS) ? pS : pD;
        int hb = bx - ((bx < SB_HS) ? SB_SENT : SB_HS);
        for (int w = t; w < HWORDS; w += 256) h[w] = 0u;
        __syncthreads();
        int base = hb * HCHUNK;
        for (int i = t; i < HCHUNK; i += 256) {
            int s = idx[base + i];
            atomicAdd(&h[s >> 2], 1u << ((s & 3) << 3));
        }
        __syncthreads();
        outp += (size_t)hb * HWORDS;
        for (int w = t; w < HWORDS; w += 256) outp[w] = h[w];
        return;
    }
    int vb = bx - SB_HD;                 // 0..65
    if (vb == 65) {
        if (t < 64) {                    // zero the sentinel row in both buffers
            int qq = t >> 4, c2 = t & 15;
            Y0[(size_t)qq * SLICE + ((size_t)ZROW << 4) + c2] = 0.f;
            Y1[(size_t)qq * SLICE + ((size_t)ZROW << 4) + c2] = 0.f;
        }
        if (t == 64) bar[0] = 0u;        // reset grid-barrier counter every replay
        return;
    }
    if (vb == 64) {
        if (t < DOUT) {
            float s = 0.f;
            for (int k = 0; k < DHID; ++k) s += b1[k] * W3[k * DOUT + t];
            bb[t] = s;
        }
        return;
    }
    int idx2 = vb * 256 + t;             // 16384 outputs of W13 = W1@W3
    int i = idx2 >> 6, j = idx2 & 63;
    float s = 0.f;
    for (int k = 0; k < DHID; ++k) s += W1[i * DHID + k] * W3[k * DOUT + j];
    W13[idx2] = s;
}

// ---------------- hpre: 4-way-parallel scan + reduce + norms + degree hist ----------------
__global__ void k_hpre(const unsigned int* __restrict__ pS,
                       const unsigned int* __restrict__ pD,
                       unsigned int* __restrict__ prefix,
                       int* __restrict__ deg_in,
                       float* __restrict__ ns, float* __restrict__ nd,
                       float* __restrict__ cc, int* __restrict__ dparts) {
    __shared__ unsigned int sdw[64][4];
    __shared__ unsigned int sow[64][4];
    __shared__ int lh[65];
    int t = threadIdx.x;
    if (t < 65) lh[t] = 0;
    int col = t >> 2, sub = t & 3;
    int wid = blockIdx.x * 64 + col;
    bool act = wid < HWORDS;
    unsigned int ps = 0, pd = 0;
    if (act) {
        int b0 = sub << 6;
#pragma unroll 4
        for (int b = b0; b < b0 + 64; ++b) {
            ps += pS[(size_t)b * HWORDS + wid];
            pd += pD[(size_t)b * HWORDS + wid];
        }
    }
    sdw[col][sub] = pd;
    sow[col][sub] = ps;
    __syncthreads();
    if (act) {
        unsigned int base = 0;
        for (int k = 0; k < sub; ++k) base += sdw[col][k];
        int b0 = sub << 6;
        unsigned int run = base;
        for (int b = b0; b < b0 + 64; ++b) {
            unsigned int w = pD[(size_t)b * HWORDS + wid];
            prefix[(size_t)b * HWORDS + wid] = run;
            run += w;
        }
        if (sub == 0) {
            unsigned int totd = sdw[col][0] + sdw[col][1] + sdw[col][2] + sdw[col][3];
            unsigned int toto = sow[col][0] + sow[col][1] + sow[col][2] + sow[col][3];
            unsigned int di[4] = {totd & 0xffu, (totd >> 8) & 0xffu,
                                  (totd >> 16) & 0xffu, totd >> 24};
            unsigned int dov[4] = {toto & 0xffu, (toto >> 8) & 0xffu,
                                   (toto >> 16) & 0xffu, toto >> 24};
            int4 dd; dd.x = (int)di[0]; dd.y = (int)di[1]; dd.z = (int)di[2]; dd.w = (int)di[3];
            *(int4*)(deg_in + (wid << 2)) = dd;
            float4 vns, vnd, vcc;
            float* pns = &vns.x; float* pnd = &vnd.x; float* pcc = &vcc.x;
#pragma unroll
            for (int q = 0; q < 4; ++q) {
                int bin = (int)di[q]; if (bin > 64) bin = 64;
                atomicAdd(&lh[bin], 1);
                unsigned int a = dov[q] < 1u ? 1u : dov[q];
                unsigned int b = di[q] < 1u ? 1u : di[q];
                float fa = 1.0f / sqrtf((float)a);
                float fb = 1.0f / sqrtf((float)b);
                pns[q] = fa; pnd[q] = fb; pcc[q] = fa * fb;
            }
            *(float4*)(ns + (wid << 2)) = vns;
            *(float4*)(nd + (wid << 2)) = vnd;
            *(float4*)(cc + (wid << 2)) = vcc;
        }
    }
    __syncthreads();
    if (t < 65) dparts[blockIdx.x * 65 + t] = lh[t];
}

// ---------------- counting-sort scan (DESCENDING degree) ----------------
__global__ void k_dscan(const int* __restrict__ dparts, int* __restrict__ offs) {
    __shared__ int colsum[65], binbase[65];
    int t = threadIdx.x;
    if (t < 65) {
        int s = 0;
        for (int b = 0; b < P2BLOCKS; ++b) s += dparts[b * 65 + t];
        colsum[t] = s;
    }
    __syncthreads();
    if (t == 0) {
        int run = 0;
        for (int k = 64; k >= 0; --k) { binbase[k] = run; run += colsum[k]; }
    }
    __syncthreads();
    if (t < 65) {
        int run = binbase[t];
        for (int b = 0; b < P2BLOCKS; ++b) { offs[b * 65 + t] = run; run += dparts[b * 65 + t]; }
    }
}

// ---------------- scatter: perm/inv + permuted degree & norm arrays ----------------
__global__ void k_dscatter(const int* __restrict__ deg_in, const int* __restrict__ offs,
                           const float* __restrict__ cc, const float* __restrict__ ns,
                           const float* __restrict__ nd,
                           int* __restrict__ perm, int* __restrict__ inv,
                           int* __restrict__ degP, float* __restrict__ ccP,
                           float* __restrict__ nsP, float* __restrict__ ndP) {
    __shared__ int off[65];
    int t = threadIdx.x;
    if (t < 65) off[t] = offs[blockIdx.x * 65 + t];
    __syncthreads();
    int wid = blockIdx.x * 64 + t;
    if (t < 64 && wid < HWORDS) {
        int4 d4 = *(const int4*)(deg_in + (wid << 2));
        int dd[4] = {d4.x, d4.y, d4.z, d4.w};
#pragma unroll
        for (int k = 0; k < 4; ++k) {
            int node = (wid << 2) + k;
            int bin = dd[k] > 64 ? 64 : dd[k];
            int slot = atomicAdd(&off[bin], 1);
            perm[slot] = node; inv[node] = slot;
            degP[slot] = dd[k];
            ccP[slot] = cc[node]; nsP[slot] = ns[node]; ndP[slot] = nd[node];
        }
    }
}

// ---------------- fill csr (renumbered space) using LDS atomics only ----------------
__global__ void k_fill(const int* __restrict__ src, const int* __restrict__ dst,
                       const unsigned int* __restrict__ prefix,
                       const int* __restrict__ inv,
                       unsigned short* __restrict__ csr) {
    __shared__ unsigned int h[HWORDS];
    int t = threadIdx.x;
    const unsigned int* prow = prefix + (size_t)blockIdx.x * HWORDS;
    for (int w = t; w < HWORDS; w += 256) h[w] = prow[w];
    __syncthreads();
    int base = blockIdx.x * HCHUNK;
    for (int i = t; i < HCHUNK; i += 256) {
        int s = src[base + i], d = dst[base + i];
        int sh = (d & 3) << 3;
        unsigned int old = atomicAdd(&h[d >> 2], 1u << sh);
        int slot = (int)((old >> sh) & 0xffu);
        csr[((size_t)inv[d] << 6) + slot] = (unsigned short)inv[s];
    }
}

// ---------------- dense GEMM: Y[inv[row]] = ns[row] ∘ (X @ W13), COLUMN-SLICED --------
__global__ void k_gemm(const float* __restrict__ X, const float* __restrict__ W13,
                       const float* __restrict__ ns, const int* __restrict__ inv,
                       float* __restrict__ Y) {
    __shared__ float As[16][68];
    __shared__ float Bs[16][64];
    int tid = threadIdx.x;
    int tx = tid & 15, ty = tid >> 4;
    int row0 = blockIdx.x * 64;
    float acc[4][4];
#pragma unroll
    for (int i = 0; i < 4; ++i)
#pragma unroll
        for (int j = 0; j < 4; ++j) acc[i][j] = 0.f;

    int lr = tid >> 2;
    int lk = (tid & 3) << 2;
    int arow = row0 + lr;
    if (arow > N_NODES - 1) arow = N_NODES - 1;   // clamp: garbage rows never stored

    for (int k0 = 0; k0 < DIN; k0 += 16) {
        float4 a = *(const float4*)(X + (size_t)arow * DIN + k0 + lk);
        As[lk + 0][lr] = a.x; As[lk + 1][lr] = a.y;
        As[lk + 2][lr] = a.z; As[lk + 3][lr] = a.w;
        float4 b = *(const float4*)(W13 + (size_t)(k0 + (tid >> 4)) * DOUT + ((tid & 15) << 2));
        *(float4*)&Bs[tid >> 4][(tid & 15) << 2] = b;
        __syncthreads();
#pragma unroll
        for (int k = 0; k < 16; ++k) {
            float4 av = *(const float4*)&As[k][ty << 2];
            float4 bv = *(const float4*)&Bs[k][tx << 2];
            float ar[4] = {av.x, av.y, av.z, av.w};
            float br[4] = {bv.x, bv.y, bv.z, bv.w};
#pragma unroll
            for (int i = 0; i < 4; ++i)
#pragma unroll
                for (int j = 0; j < 4; ++j) acc[i][j] += ar[i] * br[j];
        }
        __syncthreads();
    }
    int qq = tx >> 2;
    int co = (tx & 3) << 2;
#pragma unroll
    for (int i = 0; i < 4; ++i) {
        int row = row0 + (ty << 2) + i;
        if (row < N_NODES) {
            float nsr = ns[row];
            int prow = inv[row];
            float4 o;
            o.x = acc[i][0] * nsr; o.y = acc[i][1] * nsr;
            o.z = acc[i][2] * nsr; o.w = acc[i][3] * nsr;
            *(float4*)(Y + (size_t)qq * SLICE + ((size_t)prow << 4) + co) = o;
        }
    }
}

// ---------------- software grid barrier (no cooperative-launch machinery) ----------
// Monotonic counter in workspace (zeroed by k_setup each replay). Barrier b:
// every block adds 1, spins until cnt >= PBLOCKS*b. Agent-scope release fence
// (s_waitcnt + buffer_wbl2: pushes this XCD's dirty Y lines to the coherence
// point) before arrival; agent-scope acquire fence (buffer_inv: drops stale
// clean L1/L2 lines) after release. __syncthreads drains vmcnt on entry, so
// all waves' stores are in L2 before the writeback. Bounded spin: if blocks
// were ever not co-resident we produce a wrong answer instead of a hang.
__device__ __forceinline__ void gbar(unsigned int* bar, unsigned int target) {
    __syncthreads();
    if (threadIdx.x == 0) {
        __builtin_amdgcn_fence(__ATOMIC_RELEASE, "agent");
        __hip_atomic_fetch_add(bar, 1u, __ATOMIC_RELAXED, __HIP_MEMORY_SCOPE_AGENT);
        unsigned int guard = 0;
        while (__hip_atomic_load(bar, __ATOMIC_RELAXED, __HIP_MEMORY_SCOPE_AGENT) < target) {
            __builtin_amdgcn_s_sleep(1);
            if (++guard > (1u << 20)) break;   // failsafe: no hang
        }
        __builtin_amdgcn_fence(__ATOMIC_ACQUIRE, "agent");
    }
    __syncthreads();
}

// ---------------- one SpMM pass, executed by a persistent wave over its groups ------
// Each wave grid-strides over groups g = wq, wq+2048, ... within its fixed
// q-slice (q pinned per block -> XCD-pair L2 residency of the 3.2 MB slice
// persists ACROSS passes). Degree-sorted groups + stride-2048 stays balanced.
// MODE 0: y = cc*acc + ns*bb[col]; MODE 1: y = cc*acc;
// MODE 2: out[perm[node]] = nd*acc + b3[col]  (row-major, original numbering).

template <int MODE>
__device__ __forceinline__ void spmm_pass(
    unsigned short (*rows)[256],
    const float* __restrict__ xs, float* __restrict__ ys,
    const unsigned short* __restrict__ csr, const int* __restrict__ degP,
    const float* __restrict__ ccP, const float* __restrict__ nsP,
    const float* __restrict__ ndP, const float* __restrict__ bb,
    const float* __restrict__ b3, const int* __restrict__ perm,
    int wq, int q) {
    int wid  = threadIdx.x >> 6;
    int lane = threadIdx.x & 63;
    int nn = lane >> 4, sl = lane & 15;
    int n = lane >> 4, e = (lane >> 2) & 3, c4 = lane & 3;
    const float* xq = xs + (size_t)q * SLICE + (c4 << 2);
    const unsigned short* rd = &rows[wid][(e << 2) + n];   // entry (e+4T) at rd[16T]

    for (int g = wq; g < NGROUPS; g += PWAVES_Q) {
        int node0 = g << 2;

        // stage 4 csr rows (4 x 128 B) into LDS, transposed: lane (nn,sl) loads
        // entries 4sl..4sl+3 of node nn and writes them at [(4sl+k)*4 + nn].
        const uint2* crow = (const uint2*)(csr + ((size_t)(node0 + nn) << 6)) + sl;
        uint2 rv = *crow;
        unsigned short* bp = &rows[wid][(sl << 4) + nn];
        bp[0]  = (unsigned short)(rv.x & 0xffffu);
        bp[4]  = (unsigned short)(rv.x >> 16);
        bp[8]  = (unsigned short)(rv.y & 0xffffu);
        bp[12] = (unsigned short)(rv.y >> 16);

        int n0u = __builtin_amdgcn_readfirstlane(node0);
        int m = (degP[n0u] + 7) & ~7;        // group max (descending sort)

        float ax = 0.f, ay = 0.f, az = 0.f, aw = 0.f;
#define LDV(T) const float4 v##T = *(const float4*)(xq + ((size_t)rd[16 * (T)] << 4))
#define ACCV(T) ax += v##T.x; ay += v##T.y; az += v##T.z; aw += v##T.w
        if (m <= 8) {
            LDV(0); LDV(1);
            ACCV(0); ACCV(1);
        } else if (m <= 16) {
            LDV(0); LDV(1); LDV(2); LDV(3);
            ACCV(0); ACCV(1); ACCV(2); ACCV(3);
        } else if (m <= 24) {
            LDV(0); LDV(1); LDV(2); LDV(3); LDV(4); LDV(5);
            ACCV(0); ACCV(1); ACCV(2); ACCV(3); ACCV(4); ACCV(5);
        } else if (m <= 32) {
            LDV(0); LDV(1); LDV(2); LDV(3); LDV(4); LDV(5); LDV(6); LDV(7);
            ACCV(0); ACCV(1); ACCV(2); ACCV(3); ACCV(4); ACCV(5); ACCV(6); ACCV(7);
        } else {
            for (int j2 = 0; j2 < m; j2 += 8) {
                int o = j2 << 2;
                const float4 a = *(const float4*)(xq + ((size_t)rd[o] << 4));
                const float4 b = *(const float4*)(xq + ((size_t)rd[o + 16] << 4));
                ax += a.x; ay += a.y; az += a.z; aw += a.w;
                ax += b.x; ay += b.y; az += b.z; aw += b.w;
            }
        }
#undef LDV
#undef ACCV
        // reduce over edge-slots e (lane bits 2..3)
        ax += __shfl_xor(ax, 4);  ay += __shfl_xor(ay, 4);
        az += __shfl_xor(az, 4);  aw += __shfl_xor(aw, 4);
        ax += __shfl_xor(ax, 8);  ay += __shfl_xor(ay, 8);
        az += __shfl_xor(az, 8);  aw += __shfl_xor(aw, 8);

        int nodeL = node0 + n;
        int colq  = (q << 4) + (c4 << 2);
        float4 r;
        if (MODE == 0) {
            float cv = ccP[nodeL], nv = nsP[nodeL];
            float4 bv = *(const float4*)(bb + colq);
            r.x = cv * ax + nv * bv.x; r.y = cv * ay + nv * bv.y;
            r.z = cv * az + nv * bv.z; r.w = cv * aw + nv * bv.w;
        } else if (MODE == 1) {
            float cv = ccP[nodeL];
            r.x = cv * ax; r.y = cv * ay; r.z = cv * az; r.w = cv * aw;
        } else {
            float dv = ndP[nodeL];
            float4 bv = *(const float4*)(b3 + colq);
            r.x = dv * ax + bv.x; r.y = dv * ay + bv.y;
            r.z = dv * az + bv.z; r.w = dv * aw + bv.w;
        }
        if (e == 0) {
            if (MODE == 2) {
                int orow = perm[nodeL];
                *(float4*)(ys + ((size_t)orow << 6) + colq) = r;
            } else {
                *(float4*)(ys + (size_t)q * SLICE + ((size_t)nodeL << 4) + (c4 << 2)) = r;
            }
        }
    }
}

// ---------------- persistent kernel: all 6 propagation passes, software barrier ----
__global__ __launch_bounds__(256, 8) void k_fused(
    float* __restrict__ Y0, float* __restrict__ Y1,
    const unsigned short* __restrict__ csr, const int* __restrict__ degP,
    const float* __restrict__ ccP, const float* __restrict__ nsP,
    const float* __restrict__ ndP, const float* __restrict__ bb,
    const float* __restrict__ b3, const int* __restrict__ perm,
    float* __restrict__ out, unsigned int* bar) {
    __shared__ unsigned short rows[4][256];     // [wave][entry*4 + node] = 2 KB
    int bx  = (int)blockIdx.x;
    int wid = threadIdx.x >> 6;
    int q   = (bx & 7) >> 1;                     // q pinned per block -> XCD-pair L2
    int wq  = (((bx >> 3) << 1) | (bx & 1)) * 4 + wid;   // 0..2047 within q-class

    spmm_pass<0>(rows, Y0, Y1, csr, degP, ccP, nsP, ndP, bb, b3, perm, wq, q);
    gbar(bar, PBLOCKS * 1u);
    spmm_pass<1>(rows, Y1, Y0, csr, degP, ccP, nsP, ndP, bb, b3, perm, wq, q);
    gbar(bar, PBLOCKS * 2u);
    spmm_pass<1>(rows, Y0, Y1, csr, degP, ccP, nsP, ndP, bb, b3, perm, wq, q);
    gbar(bar, PBLOCKS * 3u);
    spmm_pass<1>(rows, Y1, Y0, csr, degP, ccP, nsP, ndP, bb, b3, perm, wq, q);
    gbar(bar, PBLOCKS * 4u);
    spmm_pass<1>(rows, Y0, Y1, csr, degP, ccP, nsP, ndP, bb, b3, perm, wq, q);
    gbar(bar, PBLOCKS * 5u);
    spmm_pass<2>(rows, Y1, out, csr, degP, ccP, nsP, ndP, bb, b3, perm, wq, q);
}

// ---------------- launcher ----------------

extern "C" void kernel_launch(void* const* d_in, const int* in_sizes, int n_in,
                              void* d_out, int out_size, void* d_ws, size_t ws_size,
                              hipStream_t stream) {
    const float* X   = (const float*)d_in[0];
    const int*   src = (const int*)d_in[1];
    const int*   dst = (const int*)d_in[2];
    const float* W1  = (const float*)d_in[3];
    const float* b1  = (const float*)d_in[4];
    const float* W3  = (const float*)d_in[5];
    const float* b3  = (const float*)d_in[6];
    float* out = (float*)d_out;

    char* ws = (char*)d_ws;
    size_t off = 0;
    auto alloc = [&](size_t bytes) -> void* {
        void* p = ws + off;
        off = (off + bytes + 255) & ~(size_t)255;
        return p;
    };
    unsigned int*   pS     = (unsigned int*)alloc((size_t)HBLOCKS * HWORDS * 4);
    unsigned int*   pD     = (unsigned int*)alloc((size_t)HBLOCKS * HWORDS * 4);
    unsigned int*   pref   = (unsigned int*)alloc((size_t)HBLOCKS * HWORDS * 4);
    float*          Y0     = (float*)alloc(SLICE * 4 * 4);
    float*          Y1     = (float*)alloc(SLICE * 4 * 4);
    unsigned short* csr    = (unsigned short*)alloc((size_t)N_NODES * CSTRIDE * 2);
    int*            deg_in = (int*)alloc((size_t)N_NODES * 4);
    float*          ns     = (float*)alloc((size_t)N_NODES * 4);
    float*          nd     = (float*)alloc((size_t)N_NODES * 4);
    float*          cc     = (float*)alloc((size_t)N_NODES * 4);
    int*            perm   = (int*)alloc((size_t)N_NODES * 4);
    int*            inv    = (int*)alloc((size_t)N_NODES * 4);
    int*            degP   = (int*)alloc((size_t)N_NODES * 4);
    float*          ccP    = (float*)alloc((size_t)N_NODES * 4);
    float*          nsP    = (float*)alloc((size_t)N_NODES * 4);
    float*          ndP    = (float*)alloc((size_t)N_NODES * 4);
    int*            dparts = (int*)alloc((size_t)P2BLOCKS * 65 * 4);
    int*            offs   = (int*)alloc((size_t)P2BLOCKS * 65 * 4);
    float*          W13    = (float*)alloc((size_t)DIN * DOUT * 4);
    float*          bb     = (float*)alloc(DOUT * 4);
    unsigned int*   bar    = (unsigned int*)alloc(256);

    k_setup<<<SB_TOT, 256, 0, stream>>>(src, dst, pS, pD, (unsigned int*)csr,
                                        W1, b1, W3, W13, bb, Y0, Y1, bar);
    k_hpre<<<P2BLOCKS, 256, 0, stream>>>(pS, pD, pref, deg_in, ns, nd, cc, dparts);
    k_dscan<<<1, 128, 0, stream>>>(dparts, offs);
    k_dscatter<<<P2BLOCKS, 128, 0, stream>>>(deg_in, offs, cc, ns, nd,
                                             perm, inv, degP, ccP, nsP, ndP);
    k_fill<<<HBLOCKS, 256, 0, stream>>>(src, dst, pref, inv, csr);

    // Y0 = ns ∘ (X @ (W1@W3)), column-sliced, renumbered rows
    k_gemm<<<(N_NODES + 63) / 64, 256, 0, stream>>>(X, W13, ns, inv, Y0);

    // all 6 propagation passes in one persistent kernel with software barrier
    k_fused<<<PBLOCKS, 256, 0, stream>>>(Y0, Y1, csr, degP, ccP, nsP, ndP,
                                         bb, b3, perm, out, bar);
}

// Round 3
// 309.411 us; speedup vs baseline: 5.3738x; 5.3738x over previous
//
#include <hip/hip_runtime.h>
#include <math.h>

#define N_NODES 50000
#define N_EDGES 800000
#define DIN 256
#define DHID 128
#define DOUT 64
// Padded CSR row stride. In-degree ~ Poisson(16); P(deg > 64) ~ 1e-19 -> safe.
#define CSTRIDE 64
#define ZROW N_NODES            // sentinel row (kept zero)
#define HBLOCKS 128
#define HCHUNK (N_EDGES / HBLOCKS)     // 6250
#define HWORDS (N_NODES / 4)           // 12500
#define SLICE ((size_t)(N_NODES + 1) * 16)
#define NGROUPS (N_NODES / 4)          // 12500
#define NPAIRS (NGROUPS / 2)           // 6250 group-pairs (8 nodes each)
#define P2BLOCKS 196                   // hpre/dscatter blocks (12500/64 word-cols)

// ---------------- fat setup kernel: sentinel-fill csr, 2 histograms, weight folds ----
#define SB_SENT 3125
#define SB_HS (SB_SENT + HBLOCKS)       // 3253
#define SB_HD (SB_HS + HBLOCKS)         // 3381
#define SB_TOT (SB_HD + 66)             // 3447

__global__ void k_setup(const int* __restrict__ src, const int* __restrict__ dst,
                        unsigned int* __restrict__ pS, unsigned int* __restrict__ pD,
                        unsigned int* __restrict__ csr32,
                        const float* __restrict__ W1, const float* __restrict__ b1,
                        const float* __restrict__ W3,
                        float* __restrict__ W13, float* __restrict__ bb,
                        float* __restrict__ Y0, float* __restrict__ Y1) {
    __shared__ unsigned int h[HWORDS];
    int bx = blockIdx.x, t = threadIdx.x;
    if (bx < SB_SENT) {
        // pre-fill every csr slot with the sentinel (k_fill overwrites [0,deg))
        unsigned int v = (unsigned int)ZROW | ((unsigned int)ZROW << 16);
        uint2 o; o.x = v; o.y = v;
        ((uint2*)csr32)[bx * 256 + t] = o;
        return;
    }
    if (bx < SB_HD) {
        // byte-packed LDS-privatized histogram (4 bins per u32); per-block
        // per-node counts <= total degree (<=64) << 255 -> no byte carry.
        const int* idx = (bx < SB_HS) ? src : dst;
        unsigned int* outp = (bx < SB_HS) ? pS : pD;
        int hb = bx - ((bx < SB_HS) ? SB_SENT : SB_HS);
        for (int w = t; w < HWORDS; w += 256) h[w] = 0u;
        __syncthreads();
        int base = hb * HCHUNK;
        for (int i = t; i < HCHUNK; i += 256) {
            int s = idx[base + i];
            atomicAdd(&h[s >> 2], 1u << ((s & 3) << 3));
        }
        __syncthreads();
        outp += (size_t)hb * HWORDS;
        for (int w = t; w < HWORDS; w += 256) outp[w] = h[w];
        return;
    }
    int vb = bx - SB_HD;                 // 0..65
    if (vb == 65) {
        if (t < 64) {                    // zero the sentinel row in both buffers
            int qq = t >> 4, c2 = t & 15;
            Y0[(size_t)qq * SLICE + ((size_t)ZROW << 4) + c2] = 0.f;
            Y1[(size_t)qq * SLICE + ((size_t)ZROW << 4) + c2] = 0.f;
        }
        return;
    }
    if (vb == 64) {
        if (t < DOUT) {
            float s = 0.f;
            for (int k = 0; k < DHID; ++k) s += b1[k] * W3[k * DOUT + t];
            bb[t] = s;
        }
        return;
    }
    int idx2 = vb * 256 + t;             // 16384 outputs of W13 = W1@W3
    int i = idx2 >> 6, j = idx2 & 63;
    float s = 0.f;
    for (int k = 0; k < DHID; ++k) s += W1[i * DHID + k] * W3[k * DOUT + j];
    W13[idx2] = s;
}

// ---------------- hpre: 4-way-parallel scan + reduce + norms + degree hist ----------------
// thread = (col, sub): col = t>>2 owns packed word wid, sub = t&3 scans 32 of
// the 128 hist blocks. Packed byte sums never carry (per-node totals <= 64).
__global__ void k_hpre(const unsigned int* __restrict__ pS,
                       const unsigned int* __restrict__ pD,
                       unsigned int* __restrict__ prefix,
                       int* __restrict__ deg_in,
                       float* __restrict__ ns, float* __restrict__ nd,
                       float* __restrict__ cc, int* __restrict__ dparts) {
    __shared__ unsigned int sdw[64][4];
    __shared__ unsigned int sow[64][4];
    __shared__ int lh[65];
    int t = threadIdx.x;
    if (t < 65) lh[t] = 0;
    int col = t >> 2, sub = t & 3;
    int wid = blockIdx.x * 64 + col;
    bool act = wid < HWORDS;
    unsigned int ps = 0, pd = 0;
    if (act) {
        int b0 = sub << 5;
#pragma unroll 4
        for (int b = b0; b < b0 + 32; ++b) {
            ps += pS[(size_t)b * HWORDS + wid];
            pd += pD[(size_t)b * HWORDS + wid];
        }
    }
    sdw[col][sub] = pd;
    sow[col][sub] = ps;
    __syncthreads();
    if (act) {
        unsigned int base = 0;
        for (int k = 0; k < sub; ++k) base += sdw[col][k];
        int b0 = sub << 5;
        unsigned int run = base;
        for (int b = b0; b < b0 + 32; ++b) {
            unsigned int w = pD[(size_t)b * HWORDS + wid];
            prefix[(size_t)b * HWORDS + wid] = run;
            run += w;
        }
        if (sub == 0) {
            unsigned int totd = sdw[col][0] + sdw[col][1] + sdw[col][2] + sdw[col][3];
            unsigned int toto = sow[col][0] + sow[col][1] + sow[col][2] + sow[col][3];
            unsigned int di[4] = {totd & 0xffu, (totd >> 8) & 0xffu,
                                  (totd >> 16) & 0xffu, totd >> 24};
            unsigned int dov[4] = {toto & 0xffu, (toto >> 8) & 0xffu,
                                   (toto >> 16) & 0xffu, toto >> 24};
            int4 dd; dd.x = (int)di[0]; dd.y = (int)di[1]; dd.z = (int)di[2]; dd.w = (int)di[3];
            *(int4*)(deg_in + (wid << 2)) = dd;
            float4 vns, vnd, vcc;
            float* pns = &vns.x; float* pnd = &vnd.x; float* pcc = &vcc.x;
#pragma unroll
            for (int q = 0; q < 4; ++q) {
                int bin = (int)di[q]; if (bin > 64) bin = 64;
                atomicAdd(&lh[bin], 1);
                unsigned int a = dov[q] < 1u ? 1u : dov[q];
                unsigned int b = di[q] < 1u ? 1u : di[q];
                float fa = 1.0f / sqrtf((float)a);
                float fb = 1.0f / sqrtf((float)b);
                pns[q] = fa; pnd[q] = fb; pcc[q] = fa * fb;
            }
            *(float4*)(ns + (wid << 2)) = vns;
            *(float4*)(nd + (wid << 2)) = vnd;
            *(float4*)(cc + (wid << 2)) = vcc;
        }
    }
    __syncthreads();
    if (t < 65) dparts[blockIdx.x * 65 + t] = lh[t];
}

// ---------------- scatter: perm/inv + permuted degree & norm arrays ----------------
// The former 1-block k_dscan (pure serialization + a dispatch boundary) is
// folded in: every block redundantly computes the global counting-sort scan
// from the 51 KB dparts table (L2-hot broadcast read, ~free).
__global__ void k_dscatter(const int* __restrict__ deg_in, const int* __restrict__ dparts,
                           const float* __restrict__ cc, const float* __restrict__ ns,
                           const float* __restrict__ nd,
                           int* __restrict__ perm, int* __restrict__ inv,
                           int* __restrict__ degP, float* __restrict__ ccP,
                           float* __restrict__ nsP, float* __restrict__ ndP) {
    __shared__ int colsum[65], pre[65], off[65];
    int t = threadIdx.x;
    if (t < 65) {
        int tot = 0, pr = 0;
        int mybx = (int)blockIdx.x;
        for (int b = 0; b < P2BLOCKS; ++b) {
            int v = dparts[b * 65 + t];
            tot += v;
            if (b < mybx) pr += v;
        }
        colsum[t] = tot; pre[t] = pr;
    }
    __syncthreads();
    if (t == 0) {
        int run = 0;
        for (int k = 64; k >= 0; --k) { int c = colsum[k]; colsum[k] = run; run += c; }
        // colsum[] now holds binbase[] (descending-degree exclusive scan)
    }
    __syncthreads();
    if (t < 65) off[t] = colsum[t] + pre[t];
    __syncthreads();
    int wid = blockIdx.x * 64 + t;
    if (t < 64 && wid < HWORDS) {
        int4 d4 = *(const int4*)(deg_in + (wid << 2));
        int dd[4] = {d4.x, d4.y, d4.z, d4.w};
#pragma unroll
        for (int k = 0; k < 4; ++k) {
            int node = (wid << 2) + k;
            int bin = dd[k] > 64 ? 64 : dd[k];
            int slot = atomicAdd(&off[bin], 1);
            perm[slot] = node; inv[node] = slot;
            degP[slot] = dd[k];
            ccP[slot] = cc[node]; nsP[slot] = ns[node]; ndP[slot] = nd[node];
        }
    }
}

// ---------------- fill csr (renumbered space) using LDS atomics only ----------------
__global__ void k_fill(const int* __restrict__ src, const int* __restrict__ dst,
                       const unsigned int* __restrict__ prefix,
                       const int* __restrict__ inv,
                       unsigned short* __restrict__ csr) {
    __shared__ unsigned int h[HWORDS];
    int t = threadIdx.x;
    const unsigned int* prow = prefix + (size_t)blockIdx.x * HWORDS;
    for (int w = t; w < HWORDS; w += 256) h[w] = prow[w];
    __syncthreads();
    int base = blockIdx.x * HCHUNK;
    for (int i = t; i < HCHUNK; i += 256) {
        int s = src[base + i], d = dst[base + i];
        int sh = (d & 3) << 3;
        unsigned int old = atomicAdd(&h[d >> 2], 1u << sh);
        int slot = (int)((old >> sh) & 0xffu);
        csr[((size_t)inv[d] << 6) + slot] = (unsigned short)inv[s];
    }
}

// ---------------- dense GEMM: Y[inv[row]] = ns[row] ∘ (X @ W13), COLUMN-SLICED --------
__global__ void k_gemm(const float* __restrict__ X, const float* __restrict__ W13,
                       const float* __restrict__ ns, const int* __restrict__ inv,
                       float* __restrict__ Y) {
    __shared__ float As[16][68];
    __shared__ float Bs[16][64];
    int tid = threadIdx.x;
    int tx = tid & 15, ty = tid >> 4;
    int row0 = blockIdx.x * 64;
    float acc[4][4];
#pragma unroll
    for (int i = 0; i < 4; ++i)
#pragma unroll
        for (int j = 0; j < 4; ++j) acc[i][j] = 0.f;

    int lr = tid >> 2;
    int lk = (tid & 3) << 2;
    int arow = row0 + lr;
    if (arow > N_NODES - 1) arow = N_NODES - 1;   // clamp: garbage rows never stored

    for (int k0 = 0; k0 < DIN; k0 += 16) {
        float4 a = *(const float4*)(X + (size_t)arow * DIN + k0 + lk);
        As[lk + 0][lr] = a.x; As[lk + 1][lr] = a.y;
        As[lk + 2][lr] = a.z; As[lk + 3][lr] = a.w;
        float4 b = *(const float4*)(W13 + (size_t)(k0 + (tid >> 4)) * DOUT + ((tid & 15) << 2));
        *(float4*)&Bs[tid >> 4][(tid & 15) << 2] = b;
        __syncthreads();
#pragma unroll
        for (int k = 0; k < 16; ++k) {
            float4 av = *(const float4*)&As[k][ty << 2];
            float4 bv = *(const float4*)&Bs[k][tx << 2];
            float ar[4] = {av.x, av.y, av.z, av.w};
            float br[4] = {bv.x, bv.y, bv.z, bv.w};
#pragma unroll
            for (int i = 0; i < 4; ++i)
#pragma unroll
                for (int j = 0; j < 4; ++j) acc[i][j] += ar[i] * br[j];
        }
        __syncthreads();
    }
    int qq = tx >> 2;
    int co = (tx & 3) << 2;
#pragma unroll
    for (int i = 0; i < 4; ++i) {
        int row = row0 + (ty << 2) + i;
        if (row < N_NODES) {
            float nsr = ns[row];
            int prow = inv[row];
            float4 o;
            o.x = acc[i][0] * nsr; o.y = acc[i][1] * nsr;
            o.z = acc[i][2] * nsr; o.w = acc[i][3] * nsr;
            *(float4*)(Y + (size_t)qq * SLICE + ((size_t)prow << 4) + co) = o;
        }
    }
}

// ---------------- sliced pull SpMM, degree-sorted, TWO groups per wave --------------
// Each wave owns a PAIR of adjacent sorted groups (8 nodes): doubles loads in
// flight (typ. 4 -> 8) and halves loop/branch/readfirstlane overhead vs the
// 1-group version. Adjacent groups in descending-degree order -> shared loop
// bound m = pad8(degP[node0]) (first node = max of all 8). LDS rows stored
// TRANSPOSED [entry*4 + node] per group; group B at +256 entries.
// MODE 0: y = cc*acc + ns*bb[col]; MODE 1: y = cc*acc;
// MODE 2: out[perm[node]] = nd*acc + b3[col]  (row-major, original numbering).

template <int MODE>
__launch_bounds__(256, 8)
__global__ void k_spmm(const float* __restrict__ xs, float* __restrict__ ys,
                       const unsigned short* __restrict__ csr,
                       const int* __restrict__ degP,
                       const float* __restrict__ ccP, const float* __restrict__ nsP,
                       const float* __restrict__ ndP,
                       const float* __restrict__ bb, const float* __restrict__ b3,
                       const int* __restrict__ perm) {
    __shared__ unsigned short rows[4][512];     // [wave][grp*256 + entry*4 + node] = 4 KB
    int wid  = threadIdx.x >> 6;
    int lane = threadIdx.x & 63;
    int q    = (blockIdx.x & 7) >> 1;
    int half = blockIdx.x & 1;
    int p    = (blockIdx.x >> 3) * 8 + wid * 2 + half;   // pair id
    if (p >= NPAIRS) return;
    int node0 = p << 3;                                   // 8 consecutive sorted nodes

    // stage 8 csr rows (8 x 128 B) into LDS, transposed: lane (nn,sl) loads
    // entries 4sl..4sl+3 of nodes node0+nn (grpA) and node0+4+nn (grpB).
    int nn = lane >> 4, sl = lane & 15;
    const uint2* crowA = (const uint2*)(csr + ((size_t)(node0 + nn) << 6)) + sl;
    const uint2* crowB = (const uint2*)(csr + ((size_t)(node0 + 4 + nn) << 6)) + sl;
    uint2 rva = *crowA;
    uint2 rvb = *crowB;
    unsigned short* bpA = &rows[wid][(sl << 4) + nn];
    unsigned short* bpB = bpA + 256;
    bpA[0]  = (unsigned short)(rva.x & 0xffffu);
    bpA[4]  = (unsigned short)(rva.x >> 16);
    bpA[8]  = (unsigned short)(rva.y & 0xffffu);
    bpA[12] = (unsigned short)(rva.y >> 16);
    bpB[0]  = (unsigned short)(rvb.x & 0xffffu);
    bpB[4]  = (unsigned short)(rvb.x >> 16);
    bpB[8]  = (unsigned short)(rvb.y & 0xffffu);
    bpB[12] = (unsigned short)(rvb.y >> 16);

    int n0u = __builtin_amdgcn_readfirstlane(node0);
    int m = (degP[n0u] + 7) & ~7;        // max over all 8 nodes (descending sort)

    int n = lane >> 4, e = (lane >> 2) & 3, c4 = lane & 3;
    const unsigned short* rdA = &rows[wid][(e << 2) + n];   // entry (e+4T) at rdA[16T]
    const unsigned short* rdB = rdA + 256;
    const float* xq = xs + (size_t)q * SLICE + (c4 << 2);

    float aAx = 0.f, aAy = 0.f, aAz = 0.f, aAw = 0.f;
    float aBx = 0.f, aBy = 0.f, aBz = 0.f, aBw = 0.f;
#define LDA(T) const float4 vA##T = *(const float4*)(xq + ((size_t)rdA[16 * (T)] << 4))
#define LDB(T) const float4 vB##T = *(const float4*)(xq + ((size_t)rdB[16 * (T)] << 4))
#define ACA(T) aAx += vA##T.x; aAy += vA##T.y; aAz += vA##T.z; aAw += vA##T.w
#define ACB(T) aBx += vB##T.x; aBy += vB##T.y; aBz += vB##T.z; aBw += vB##T.w
    if (m <= 8) {
        LDA(0); LDA(1); LDB(0); LDB(1);
        ACA(0); ACA(1); ACB(0); ACB(1);
    } else if (m <= 16) {
        LDA(0); LDA(1); LDA(2); LDA(3); LDB(0); LDB(1); LDB(2); LDB(3);
        ACA(0); ACA(1); ACA(2); ACA(3); ACB(0); ACB(1); ACB(2); ACB(3);
    } else if (m <= 24) {
        LDA(0); LDA(1); LDA(2); LDA(3); LDA(4); LDA(5);
        LDB(0); LDB(1);
        ACA(0); ACA(1); ACA(2); ACA(3);
        LDB(2); LDB(3); LDB(4); LDB(5);
        ACA(4); ACA(5);
        ACB(0); ACB(1); ACB(2); ACB(3); ACB(4); ACB(5);
    } else if (m <= 32) {
        LDA(0); LDA(1); LDA(2); LDA(3); LDB(0); LDB(1); LDB(2); LDB(3);
        ACA(0); ACA(1); ACA(2); ACA(3); ACB(0); ACB(1); ACB(2); ACB(3);
        LDA(4); LDA(5); LDA(6); LDA(7); LDB(4); LDB(5); LDB(6); LDB(7);
        ACA(4); ACA(5); ACA(6); ACA(7); ACB(4); ACB(5); ACB(6); ACB(7);
    } else {
        for (int j2 = 0; j2 < m; j2 += 8) {
            int o = j2 << 2;
            const float4 a0 = *(const float4*)(xq + ((size_t)rdA[o] << 4));
            const float4 a1 = *(const float4*)(xq + ((size_t)rdA[o + 16] << 4));
            const float4 b0 = *(const float4*)(xq + ((size_t)rdB[o] << 4));
            const float4 b1 = *(const float4*)(xq + ((size_t)rdB[o + 16] << 4));
            aAx += a0.x; aAy += a0.y; aAz += a0.z; aAw += a0.w;
            aAx += a1.x; aAy += a1.y; aAz += a1.z; aAw += a1.w;
            aBx += b0.x; aBy += b0.y; aBz += b0.z; aBw += b0.w;
            aBx += b1.x; aBy += b1.y; aBz += b1.z; aBw += b1.w;
        }
    }
#undef LDA
#undef LDB
#undef ACA
#undef ACB
    // reduce over edge-slots e (lane bits 2..3), both groups
    aAx += __shfl_xor(aAx, 4);  aAy += __shfl_xor(aAy, 4);
    aAz += __shfl_xor(aAz, 4);  aAw += __shfl_xor(aAw, 4);
    aBx += __shfl_xor(aBx, 4);  aBy += __shfl_xor(aBy, 4);
    aBz += __shfl_xor(aBz, 4);  aBw += __shfl_xor(aBw, 4);
    aAx += __shfl_xor(aAx, 8);  aAy += __shfl_xor(aAy, 8);
    aAz += __shfl_xor(aAz, 8);  aAw += __shfl_xor(aAw, 8);
    aBx += __shfl_xor(aBx, 8);  aBy += __shfl_xor(aBy, 8);
    aBz += __shfl_xor(aBz, 8);  aBw += __shfl_xor(aBw, 8);

    int nodeA = node0 + n;
    int nodeB = node0 + 4 + n;
    int colq  = (q << 4) + (c4 << 2);
    float4 rA, rB;
    if (MODE == 0) {
        float4 bv = *(const float4*)(bb + colq);
        float cvA = ccP[nodeA], nvA = nsP[nodeA];
        rA.x = cvA * aAx + nvA * bv.x; rA.y = cvA * aAy + nvA * bv.y;
        rA.z = cvA * aAz + nvA * bv.z; rA.w = cvA * aAw + nvA * bv.w;
        float cvB = ccP[nodeB], nvB = nsP[nodeB];
        rB.x = cvB * aBx + nvB * bv.x; rB.y = cvB * aBy + nvB * bv.y;
        rB.z = cvB * aBz + nvB * bv.z; rB.w = cvB * aBw + nvB * bv.w;
    } else if (MODE == 1) {
        float cvA = ccP[nodeA];
        rA.x = cvA * aAx; rA.y = cvA * aAy; rA.z = cvA * aAz; rA.w = cvA * aAw;
        float cvB = ccP[nodeB];
        rB.x = cvB * aBx; rB.y = cvB * aBy; rB.z = cvB * aBz; rB.w = cvB * aBw;
    } else {
        float4 bv = *(const float4*)(b3 + colq);
        float dvA = ndP[nodeA];
        rA.x = dvA * aAx + bv.x; rA.y = dvA * aAy + bv.y;
        rA.z = dvA * aAz + bv.z; rA.w = dvA * aAw + bv.w;
        float dvB = ndP[nodeB];
        rB.x = dvB * aBx + bv.x; rB.y = dvB * aBy + bv.y;
        rB.z = dvB * aBz + bv.z; rB.w = dvB * aBw + bv.w;
    }
    if (e == 0) {
        if (MODE == 2) {
            int orowA = perm[nodeA];
            int orowB = perm[nodeB];
            *(float4*)(ys + ((size_t)orowA << 6) + colq) = rA;
            *(float4*)(ys + ((size_t)orowB << 6) + colq) = rB;
        } else {
            *(float4*)(ys + (size_t)q * SLICE + ((size_t)nodeA << 4) + (c4 << 2)) = rA;
            *(float4*)(ys + (size_t)q * SLICE + ((size_t)nodeB << 4) + (c4 << 2)) = rB;
        }
    }
}

// ---------------- launcher ----------------

extern "C" void kernel_launch(void* const* d_in, const int* in_sizes, int n_in,
                              void* d_out, int out_size, void* d_ws, size_t ws_size,
                              hipStream_t stream) {
    const float* X   = (const float*)d_in[0];
    const int*   src = (const int*)d_in[1];
    const int*   dst = (const int*)d_in[2];
    const float* W1  = (const float*)d_in[3];
    const float* b1  = (const float*)d_in[4];
    const float* W3  = (const float*)d_in[5];
    const float* b3  = (const float*)d_in[6];
    float* out = (float*)d_out;

    char* ws = (char*)d_ws;
    size_t off = 0;
    auto alloc = [&](size_t bytes) -> void* {
        void* p = ws + off;
        off = (off + bytes + 255) & ~(size_t)255;
        return p;
    };
    unsigned int*   pS     = (unsigned int*)alloc((size_t)HBLOCKS * HWORDS * 4);
    unsigned int*   pD     = (unsigned int*)alloc((size_t)HBLOCKS * HWORDS * 4);
    unsigned int*   pref   = (unsigned int*)alloc((size_t)HBLOCKS * HWORDS * 4);
    float*          Y0     = (float*)alloc(SLICE * 4 * 4);
    float*          Y1     = (float*)alloc(SLICE * 4 * 4);
    unsigned short* csr    = (unsigned short*)alloc((size_t)N_NODES * CSTRIDE * 2);
    int*            deg_in = (int*)alloc((size_t)N_NODES * 4);
    float*          ns     = (float*)alloc((size_t)N_NODES * 4);
    float*          nd     = (float*)alloc((size_t)N_NODES * 4);
    float*          cc     = (float*)alloc((size_t)N_NODES * 4);
    int*            perm   = (int*)alloc((size_t)N_NODES * 4);
    int*            inv    = (int*)alloc((size_t)N_NODES * 4);
    int*            degP   = (int*)alloc((size_t)N_NODES * 4);
    float*          ccP    = (float*)alloc((size_t)N_NODES * 4);
    float*          nsP    = (float*)alloc((size_t)N_NODES * 4);
    float*          ndP    = (float*)alloc((size_t)N_NODES * 4);
    int*            dparts = (int*)alloc((size_t)P2BLOCKS * 65 * 4);
    float*          W13    = (float*)alloc((size_t)DIN * DOUT * 4);
    float*          bb     = (float*)alloc(DOUT * 4);

    const int sblk = 782 * 8;   // 6256 blocks -> 6250 group-pairs x 4 slices

    k_setup<<<SB_TOT, 256, 0, stream>>>(src, dst, pS, pD, (unsigned int*)csr,
                                        W1, b1, W3, W13, bb, Y0, Y1);
    k_hpre<<<P2BLOCKS, 256, 0, stream>>>(pS, pD, pref, deg_in, ns, nd, cc, dparts);
    k_dscatter<<<P2BLOCKS, 128, 0, stream>>>(deg_in, dparts, cc, ns, nd,
                                             perm, inv, degP, ccP, nsP, ndP);
    k_fill<<<HBLOCKS, 256, 0, stream>>>(src, dst, pref, inv, csr);

    // Y0 = ns ∘ (X @ (W1@W3)), column-sliced, renumbered rows
    k_gemm<<<(N_NODES + 63) / 64, 256, 0, stream>>>(X, W13, ns, inv, Y0);

    // 6 propagation passes; bias bb injected in pass 1, b3 in pass 6
    k_spmm<0><<<sblk, 256, 0, stream>>>(Y0, Y1, csr, degP, ccP, nsP, ndP, bb, b3, perm);
    k_spmm<1><<<sblk, 256, 0, stream>>>(Y1, Y0, csr, degP, ccP, nsP, ndP, bb, b3, perm);
    k_spmm<1><<<sblk, 256, 0, stream>>>(Y0, Y1, csr, degP, ccP, nsP, ndP, bb, b3, perm);
    k_spmm<1><<<sblk, 256, 0, stream>>>(Y1, Y0, csr, degP, ccP, nsP, ndP, bb, b3, perm);
    k_spmm<1><<<sblk, 256, 0, stream>>>(Y0, Y1, csr, degP, ccP, nsP, ndP, bb, b3, perm);
    k_spmm<2><<<sblk, 256, 0, stream>>>(Y1, out, csr, degP, ccP, nsP, ndP, bb, b3, perm);
}

// Round 4
// 303.695 us; speedup vs baseline: 5.4749x; 1.0188x over previous
//
#include <hip/hip_runtime.h>
#include <math.h>

#define N_NODES 50000
#define N_EDGES 800000
#define DIN 256
#define DHID 128
#define DOUT 64
// Padded CSR row stride. In-degree ~ Poisson(16); P(deg > 64) ~ 1e-19 -> safe.
#define CSTRIDE 64
#define ZROW N_NODES            // sentinel row (kept zero)
#define HBLOCKS 128
#define HCHUNK (N_EDGES / HBLOCKS)     // 6250
#define HWORDS (N_NODES / 4)           // 12500
#define SLICE2 ((size_t)(N_NODES + 1) * 32)   // one of 2 column-slices, 128 B rows
#define NGROUPS (N_NODES / 4)          // 12500
#define NPAIRS (NGROUPS / 2)           // 6250 group-pairs (8 nodes each)
#define P2BLOCKS 196                   // hpre/dscatter blocks (12500/64 word-cols)

// ---------------- fat setup kernel: sentinel-fill csr, 2 histograms, weight folds ----
#define SB_SENT 3125
#define SB_HS (SB_SENT + HBLOCKS)       // 3253
#define SB_HD (SB_HS + HBLOCKS)         // 3381
#define SB_TOT (SB_HD + 66)             // 3447

__global__ void k_setup(const int* __restrict__ src, const int* __restrict__ dst,
                        unsigned int* __restrict__ pS, unsigned int* __restrict__ pD,
                        unsigned int* __restrict__ csr32,
                        const float* __restrict__ W1, const float* __restrict__ b1,
                        const float* __restrict__ W3,
                        float* __restrict__ W13, float* __restrict__ bb,
                        float* __restrict__ Y0, float* __restrict__ Y1) {
    __shared__ unsigned int h[HWORDS];
    int bx = blockIdx.x, t = threadIdx.x;
    if (bx < SB_SENT) {
        // pre-fill every csr slot with the sentinel (k_fill overwrites [0,deg))
        unsigned int v = (unsigned int)ZROW | ((unsigned int)ZROW << 16);
        uint2 o; o.x = v; o.y = v;
        ((uint2*)csr32)[bx * 256 + t] = o;
        return;
    }
    if (bx < SB_HD) {
        // byte-packed LDS-privatized histogram (4 bins per u32); per-block
        // per-node counts <= total degree (<=64) << 255 -> no byte carry.
        const int* idx = (bx < SB_HS) ? src : dst;
        unsigned int* outp = (bx < SB_HS) ? pS : pD;
        int hb = bx - ((bx < SB_HS) ? SB_SENT : SB_HS);
        for (int w = t; w < HWORDS; w += 256) h[w] = 0u;
        __syncthreads();
        int base = hb * HCHUNK;
        for (int i = t; i < HCHUNK; i += 256) {
            int s = idx[base + i];
            atomicAdd(&h[s >> 2], 1u << ((s & 3) << 3));
        }
        __syncthreads();
        outp += (size_t)hb * HWORDS;
        for (int w = t; w < HWORDS; w += 256) outp[w] = h[w];
        return;
    }
    int vb = bx - SB_HD;                 // 0..65
    if (vb == 65) {
        if (t < 64) {                    // zero the sentinel row in both buffers
            int q2 = t >> 5, c2 = t & 31;
            Y0[(size_t)q2 * SLICE2 + ((size_t)ZROW << 5) + c2] = 0.f;
            Y1[(size_t)q2 * SLICE2 + ((size_t)ZROW << 5) + c2] = 0.f;
        }
        return;
    }
    if (vb == 64) {
        if (t < DOUT) {
            float s = 0.f;
            for (int k = 0; k < DHID; ++k) s += b1[k] * W3[k * DOUT + t];
            bb[t] = s;
        }
        return;
    }
    int idx2 = vb * 256 + t;             // 16384 outputs of W13 = W1@W3
    int i = idx2 >> 6, j = idx2 & 63;
    float s = 0.f;
    for (int k = 0; k < DHID; ++k) s += W1[i * DHID + k] * W3[k * DOUT + j];
    W13[idx2] = s;
}

// ---------------- hpre: 4-way-parallel scan + reduce + norms + degree hist ----------------
// thread = (col, sub): col = t>>2 owns packed word wid, sub = t&3 scans 32 of
// the 128 hist blocks. Packed byte sums never carry (per-node totals <= 64).
__global__ void k_hpre(const unsigned int* __restrict__ pS,
                       const unsigned int* __restrict__ pD,
                       unsigned int* __restrict__ prefix,
                       int* __restrict__ deg_in,
                       float* __restrict__ ns, float* __restrict__ nd,
                       float* __restrict__ cc, int* __restrict__ dparts) {
    __shared__ unsigned int sdw[64][4];
    __shared__ unsigned int sow[64][4];
    __shared__ int lh[65];
    int t = threadIdx.x;
    if (t < 65) lh[t] = 0;
    int col = t >> 2, sub = t & 3;
    int wid = blockIdx.x * 64 + col;
    bool act = wid < HWORDS;
    unsigned int ps = 0, pd = 0;
    if (act) {
        int b0 = sub << 5;
#pragma unroll 4
        for (int b = b0; b < b0 + 32; ++b) {
            ps += pS[(size_t)b * HWORDS + wid];
            pd += pD[(size_t)b * HWORDS + wid];
        }
    }
    sdw[col][sub] = pd;
    sow[col][sub] = ps;
    __syncthreads();
    if (act) {
        unsigned int base = 0;
        for (int k = 0; k < sub; ++k) base += sdw[col][k];
        int b0 = sub << 5;
        unsigned int run = base;
        for (int b = b0; b < b0 + 32; ++b) {
            unsigned int w = pD[(size_t)b * HWORDS + wid];
            prefix[(size_t)b * HWORDS + wid] = run;
            run += w;
        }
        if (sub == 0) {
            unsigned int totd = sdw[col][0] + sdw[col][1] + sdw[col][2] + sdw[col][3];
            unsigned int toto = sow[col][0] + sow[col][1] + sow[col][2] + sow[col][3];
            unsigned int di[4] = {totd & 0xffu, (totd >> 8) & 0xffu,
                                  (totd >> 16) & 0xffu, totd >> 24};
            unsigned int dov[4] = {toto & 0xffu, (toto >> 8) & 0xffu,
                                   (toto >> 16) & 0xffu, toto >> 24};
            int4 dd; dd.x = (int)di[0]; dd.y = (int)di[1]; dd.z = (int)di[2]; dd.w = (int)di[3];
            *(int4*)(deg_in + (wid << 2)) = dd;
            float4 vns, vnd, vcc;
            float* pns = &vns.x; float* pnd = &vnd.x; float* pcc = &vcc.x;
#pragma unroll
            for (int q = 0; q < 4; ++q) {
                int bin = (int)di[q]; if (bin > 64) bin = 64;
                atomicAdd(&lh[bin], 1);
                unsigned int a = dov[q] < 1u ? 1u : dov[q];
                unsigned int b = di[q] < 1u ? 1u : di[q];
                float fa = 1.0f / sqrtf((float)a);
                float fb = 1.0f / sqrtf((float)b);
                pns[q] = fa; pnd[q] = fb; pcc[q] = fa * fb;
            }
            *(float4*)(ns + (wid << 2)) = vns;
            *(float4*)(nd + (wid << 2)) = vnd;
            *(float4*)(cc + (wid << 2)) = vcc;
        }
    }
    __syncthreads();
    if (t < 65) dparts[blockIdx.x * 65 + t] = lh[t];
}

// ---------------- scatter: perm/inv + permuted degree & norm arrays ----------------
// The former 1-block k_dscan is folded in: every block redundantly computes the
// global counting-sort scan from the 51 KB dparts table (L2-hot broadcast read).
__global__ void k_dscatter(const int* __restrict__ deg_in, const int* __restrict__ dparts,
                           const float* __restrict__ cc, const float* __restrict__ ns,
                           const float* __restrict__ nd,
                           int* __restrict__ perm, int* __restrict__ inv,
                           int* __restrict__ degP, float* __restrict__ ccP,
                           float* __restrict__ nsP, float* __restrict__ ndP) {
    __shared__ int colsum[65], pre[65], off[65];
    int t = threadIdx.x;
    if (t < 65) {
        int tot = 0, pr = 0;
        int mybx = (int)blockIdx.x;
        for (int b = 0; b < P2BLOCKS; ++b) {
            int v = dparts[b * 65 + t];
            tot += v;
            if (b < mybx) pr += v;
        }
        colsum[t] = tot; pre[t] = pr;
    }
    __syncthreads();
    if (t == 0) {
        int run = 0;
        for (int k = 64; k >= 0; --k) { int c = colsum[k]; colsum[k] = run; run += c; }
        // colsum[] now holds binbase[] (descending-degree exclusive scan)
    }
    __syncthreads();
    if (t < 65) off[t] = colsum[t] + pre[t];
    __syncthreads();
    int wid = blockIdx.x * 64 + t;
    if (t < 64 && wid < HWORDS) {
        int4 d4 = *(const int4*)(deg_in + (wid << 2));
        int dd[4] = {d4.x, d4.y, d4.z, d4.w};
#pragma unroll
        for (int k = 0; k < 4; ++k) {
            int node = (wid << 2) + k;
            int bin = dd[k] > 64 ? 64 : dd[k];
            int slot = atomicAdd(&off[bin], 1);
            perm[slot] = node; inv[node] = slot;
            degP[slot] = dd[k];
            ccP[slot] = cc[node]; nsP[slot] = ns[node]; ndP[slot] = nd[node];
        }
    }
}

// ---------------- fill csr (renumbered space) using LDS atomics only ----------------
__global__ void k_fill(const int* __restrict__ src, const int* __restrict__ dst,
                       const unsigned int* __restrict__ prefix,
                       const int* __restrict__ inv,
                       unsigned short* __restrict__ csr) {
    __shared__ unsigned int h[HWORDS];
    int t = threadIdx.x;
    const unsigned int* prow = prefix + (size_t)blockIdx.x * HWORDS;
    for (int w = t; w < HWORDS; w += 256) h[w] = prow[w];
    __syncthreads();
    int base = blockIdx.x * HCHUNK;
    for (int i = t; i < HCHUNK; i += 256) {
        int s = src[base + i], d = dst[base + i];
        int sh = (d & 3) << 3;
        unsigned int old = atomicAdd(&h[d >> 2], 1u << sh);
        int slot = (int)((old >> sh) & 0xffu);
        csr[((size_t)inv[d] << 6) + slot] = (unsigned short)inv[s];
    }
}

// ---------------- dense GEMM: Y[inv[row]] = ns[row] ∘ (X @ W13), 2-slice layout ------
__global__ void k_gemm(const float* __restrict__ X, const float* __restrict__ W13,
                       const float* __restrict__ ns, const int* __restrict__ inv,
                       float* __restrict__ Y) {
    __shared__ float As[16][68];
    __shared__ float Bs[16][64];
    int tid = threadIdx.x;
    int tx = tid & 15, ty = tid >> 4;
    int row0 = blockIdx.x * 64;
    float acc[4][4];
#pragma unroll
    for (int i = 0; i < 4; ++i)
#pragma unroll
        for (int j = 0; j < 4; ++j) acc[i][j] = 0.f;

    int lr = tid >> 2;
    int lk = (tid & 3) << 2;
    int arow = row0 + lr;
    if (arow > N_NODES - 1) arow = N_NODES - 1;   // clamp: garbage rows never stored

    for (int k0 = 0; k0 < DIN; k0 += 16) {
        float4 a = *(const float4*)(X + (size_t)arow * DIN + k0 + lk);
        As[lk + 0][lr] = a.x; As[lk + 1][lr] = a.y;
        As[lk + 2][lr] = a.z; As[lk + 3][lr] = a.w;
        float4 b = *(const float4*)(W13 + (size_t)(k0 + (tid >> 4)) * DOUT + ((tid & 15) << 2));
        *(float4*)&Bs[tid >> 4][(tid & 15) << 2] = b;
        __syncthreads();
#pragma unroll
        for (int k = 0; k < 16; ++k) {
            float4 av = *(const float4*)&As[k][ty << 2];
            float4 bv = *(const float4*)&Bs[k][tx << 2];
            float ar[4] = {av.x, av.y, av.z, av.w};
            float br[4] = {bv.x, bv.y, bv.z, bv.w};
#pragma unroll
            for (int i = 0; i < 4; ++i)
#pragma unroll
                for (int j = 0; j < 4; ++j) acc[i][j] += ar[i] * br[j];
        }
        __syncthreads();
    }
    // columns g = qq*16 + co + j -> slice g>>5 = qq>>1, offset (qq&1)*16 + co
    int qq = tx >> 2;
    int co = (tx & 3) << 2;
#pragma unroll
    for (int i = 0; i < 4; ++i) {
        int row = row0 + (ty << 2) + i;
        if (row < N_NODES) {
            float nsr = ns[row];
            int prow = inv[row];
            float4 o;
            o.x = acc[i][0] * nsr; o.y = acc[i][1] * nsr;
            o.z = acc[i][2] * nsr; o.w = acc[i][3] * nsr;
            *(float4*)(Y + (size_t)(qq >> 1) * SLICE2 + ((size_t)prow << 5)
                       + ((qq & 1) << 4) + co) = o;
        }
    }
}

// ---------------- 2-slice pull SpMM: 128 B line-sized gathers, degree-sorted --------
// Y layout: 2 slices x 32 floats (128 B rows = one L2 line). Each gather request
// is a full line -> HALF the outstanding-request count of the 4x16 layout (the
// presumed MSHR/request-rate bottleneck), same bytes. Wave = 4 nodes x 2 edge
// slots x 8 row-chunk lanes; each wave handles a PAIR of adjacent sorted groups
// (8 nodes, shared loop bound m = pad8(degP[node0])). LDS rows transposed
// [entry*4 + node] per group; group B at +256 entries. One shuffle stage (xor 8).
// q2 = (bx>>2)&1 pins slice 0 to XCDs 0-3, slice 1 to XCDs 4-7 (6.4 MB vs 16 MB L2).
// MODE 0: y = cc*acc + ns*bb[col]; MODE 1: y = cc*acc;
// MODE 2: out[perm[node]] = nd*acc + b3[col]  (row-major, original numbering).

template <int MODE>
__launch_bounds__(256, 8)
__global__ void k_spmm(const float* __restrict__ xs, float* __restrict__ ys,
                       const unsigned short* __restrict__ csr,
                       const int* __restrict__ degP,
                       const float* __restrict__ ccP, const float* __restrict__ nsP,
                       const float* __restrict__ ndP,
                       const float* __restrict__ bb, const float* __restrict__ b3,
                       const int* __restrict__ perm) {
    __shared__ unsigned short rows[4][512];     // [wave][grp*256 + entry*4 + node] = 4 KB
    int wid  = threadIdx.x >> 6;
    int lane = threadIdx.x & 63;
    int bx   = (int)blockIdx.x;
    int q2   = (bx >> 2) & 1;
    int p    = (bx >> 3) * 16 + wid * 4 + (bx & 3);      // pair id
    if (p >= NPAIRS) return;
    int node0 = p << 3;                                   // 8 consecutive sorted nodes

    // stage 8 csr rows (8 x 128 B): lane (nn,sl) loads entries 8sl..8sl+7 of
    // node nn (uint4 = 16 B), writes transposed at [(8sl+k)*4 + (nn&3)] (+256 grpB).
    int nn = lane >> 3, sl = lane & 7;
    const uint4* crow = (const uint4*)(csr + ((size_t)(node0 + nn) << 6)) + sl;
    uint4 rv = *crow;
    unsigned short* bp = &rows[wid][((nn >> 2) << 8) + (sl << 5) + (nn & 3)];
    bp[0]  = (unsigned short)(rv.x & 0xffffu);
    bp[4]  = (unsigned short)(rv.x >> 16);
    bp[8]  = (unsigned short)(rv.y & 0xffffu);
    bp[12] = (unsigned short)(rv.y >> 16);
    bp[16] = (unsigned short)(rv.z & 0xffffu);
    bp[20] = (unsigned short)(rv.z >> 16);
    bp[24] = (unsigned short)(rv.w & 0xffffu);
    bp[28] = (unsigned short)(rv.w >> 16);

    int n0u = __builtin_amdgcn_readfirstlane(node0);
    int m = (degP[n0u] + 7) & ~7;        // max over all 8 nodes (descending sort)

    int n = lane >> 4, e = (lane >> 3) & 1, c8 = lane & 7;
    const unsigned short* rdA = &rows[wid][(e << 2) + n];   // entry (2T+e) at rdA[8T]
    const unsigned short* rdB = rdA + 256;
    const float* xq = xs + (size_t)q2 * SLICE2 + (c8 << 2);

    float aAx = 0.f, aAy = 0.f, aAz = 0.f, aAw = 0.f;
    float aBx = 0.f, aBy = 0.f, aBz = 0.f, aBw = 0.f;
#define LDA(T) const float4 vA##T = *(const float4*)(xq + ((size_t)rdA[8 * (T)] << 5))
#define LDB(T) const float4 vB##T = *(const float4*)(xq + ((size_t)rdB[8 * (T)] << 5))
#define ACA(T) aAx += vA##T.x; aAy += vA##T.y; aAz += vA##T.z; aAw += vA##T.w
#define ACB(T) aBx += vB##T.x; aBy += vB##T.y; aBz += vB##T.z; aBw += vB##T.w
    if (m <= 8) {
        LDA(0); LDA(1); LDA(2); LDA(3); LDB(0); LDB(1); LDB(2); LDB(3);
        ACA(0); ACA(1); ACA(2); ACA(3); ACB(0); ACB(1); ACB(2); ACB(3);
    } else if (m <= 16) {
        LDA(0); LDA(1); LDA(2); LDA(3); LDB(0); LDB(1); LDB(2); LDB(3);
        LDA(4); LDA(5); LDA(6); LDA(7); ACA(0); ACA(1); ACA(2); ACA(3);
        LDB(4); LDB(5); LDB(6); LDB(7); ACB(0); ACB(1); ACB(2); ACB(3);
        ACA(4); ACA(5); ACA(6); ACA(7); ACB(4); ACB(5); ACB(6); ACB(7);
    } else if (m <= 24) {
        LDA(0); LDA(1); LDA(2); LDA(3); LDB(0); LDB(1); LDB(2); LDB(3);
        LDA(4); LDA(5); LDA(6); LDA(7); ACA(0); ACA(1); ACA(2); ACA(3);
        LDB(4); LDB(5); LDB(6); LDB(7); ACB(0); ACB(1); ACB(2); ACB(3);
        LDA(8); LDA(9); LDA(10); LDA(11); ACA(4); ACA(5); ACA(6); ACA(7);
        LDB(8); LDB(9); LDB(10); LDB(11); ACB(4); ACB(5); ACB(6); ACB(7);
        ACA(8); ACA(9); ACA(10); ACA(11); ACB(8); ACB(9); ACB(10); ACB(11);
    } else if (m <= 32) {
        LDA(0); LDA(1); LDA(2); LDA(3); LDB(0); LDB(1); LDB(2); LDB(3);
        LDA(4); LDA(5); LDA(6); LDA(7); ACA(0); ACA(1); ACA(2); ACA(3);
        LDB(4); LDB(5); LDB(6); LDB(7); ACB(0); ACB(1); ACB(2); ACB(3);
        LDA(8); LDA(9); LDA(10); LDA(11); ACA(4); ACA(5); ACA(6); ACA(7);
        LDB(8); LDB(9); LDB(10); LDB(11); ACB(4); ACB(5); ACB(6); ACB(7);
        LDA(12); LDA(13); LDA(14); LDA(15); ACA(8); ACA(9); ACA(10); ACA(11);
        LDB(12); LDB(13); LDB(14); LDB(15); ACB(8); ACB(9); ACB(10); ACB(11);
        ACA(12); ACA(13); ACA(14); ACA(15); ACB(12); ACB(13); ACB(14); ACB(15);
    } else {
        for (int j2 = 0; j2 < m; j2 += 8) {
            int o = j2 << 2;                 // rdA[8T], T = j2/2 .. j2/2+3
            const float4 a0 = *(const float4*)(xq + ((size_t)rdA[o] << 5));
            const float4 a1 = *(const float4*)(xq + ((size_t)rdA[o + 8] << 5));
            const float4 a2 = *(const float4*)(xq + ((size_t)rdA[o + 16] << 5));
            const float4 a3 = *(const float4*)(xq + ((size_t)rdA[o + 24] << 5));
            const float4 b0 = *(const float4*)(xq + ((size_t)rdB[o] << 5));
            const float4 b1 = *(const float4*)(xq + ((size_t)rdB[o + 8] << 5));
            const float4 b2 = *(const float4*)(xq + ((size_t)rdB[o + 16] << 5));
            const float4 b3v = *(const float4*)(xq + ((size_t)rdB[o + 24] << 5));
            aAx += a0.x; aAy += a0.y; aAz += a0.z; aAw += a0.w;
            aAx += a1.x; aAy += a1.y; aAz += a1.z; aAw += a1.w;
            aAx += a2.x; aAy += a2.y; aAz += a2.z; aAw += a2.w;
            aAx += a3.x; aAy += a3.y; aAz += a3.z; aAw += a3.w;
            aBx += b0.x; aBy += b0.y; aBz += b0.z; aBw += b0.w;
            aBx += b1.x; aBy += b1.y; aBz += b1.z; aBw += b1.w;
            aBx += b2.x; aBy += b2.y; aBz += b2.z; aBw += b2.w;
            aBx += b3v.x; aBy += b3v.y; aBz += b3v.z; aBw += b3v.w;
        }
    }
#undef LDA
#undef LDB
#undef ACA
#undef ACB
    // reduce over the 2 edge-slots (lane bit 3)
    aAx += __shfl_xor(aAx, 8);  aAy += __shfl_xor(aAy, 8);
    aAz += __shfl_xor(aAz, 8);  aAw += __shfl_xor(aAw, 8);
    aBx += __shfl_xor(aBx, 8);  aBy += __shfl_xor(aBy, 8);
    aBz += __shfl_xor(aBz, 8);  aBw += __shfl_xor(aBw, 8);

    int nodeA = node0 + n;
    int nodeB = node0 + 4 + n;
    int colq  = (q2 << 5) + (c8 << 2);
    float4 rA, rB;
    if (MODE == 0) {
        float4 bv = *(const float4*)(bb + colq);
        float cvA = ccP[nodeA], nvA = nsP[nodeA];
        rA.x = cvA * aAx + nvA * bv.x; rA.y = cvA * aAy + nvA * bv.y;
        rA.z = cvA * aAz + nvA * bv.z; rA.w = cvA * aAw + nvA * bv.w;
        float cvB = ccP[nodeB], nvB = nsP[nodeB];
        rB.x = cvB * aBx + nvB * bv.x; rB.y = cvB * aBy + nvB * bv.y;
        rB.z = cvB * aBz + nvB * bv.z; rB.w = cvB * aBw + nvB * bv.w;
    } else if (MODE == 1) {
        float cvA = ccP[nodeA];
        rA.x = cvA * aAx; rA.y = cvA * aAy; rA.z = cvA * aAz; rA.w = cvA * aAw;
        float cvB = ccP[nodeB];
        rB.x = cvB * aBx; rB.y = cvB * aBy; rB.z = cvB * aBz; rB.w = cvB * aBw;
    } else {
        float4 bv = *(const float4*)(b3 + colq);
        float dvA = ndP[nodeA];
        rA.x = dvA * aAx + bv.x; rA.y = dvA * aAy + bv.y;
        rA.z = dvA * aAz + bv.z; rA.w = dvA * aAw + bv.w;
        float dvB = ndP[nodeB];
        rB.x = dvB * aBx + bv.x; rB.y = dvB * aBy + bv.y;
        rB.z = dvB * aBz + bv.z; rB.w = dvB * aBw + bv.w;
    }
    if (e == 0) {
        if (MODE == 2) {
            int orowA = perm[nodeA];
            int orowB = perm[nodeB];
            *(float4*)(ys + ((size_t)orowA << 6) + colq) = rA;
            *(float4*)(ys + ((size_t)orowB << 6) + colq) = rB;
        } else {
            *(float4*)(ys + (size_t)q2 * SLICE2 + ((size_t)nodeA << 5) + (c8 << 2)) = rA;
            *(float4*)(ys + (size_t)q2 * SLICE2 + ((size_t)nodeB << 5) + (c8 << 2)) = rB;
        }
    }
}

// ---------------- launcher ----------------

extern "C" void kernel_launch(void* const* d_in, const int* in_sizes, int n_in,
                              void* d_out, int out_size, void* d_ws, size_t ws_size,
                              hipStream_t stream) {
    const float* X   = (const float*)d_in[0];
    const int*   src = (const int*)d_in[1];
    const int*   dst = (const int*)d_in[2];
    const float* W1  = (const float*)d_in[3];
    const float* b1  = (const float*)d_in[4];
    const float* W3  = (const float*)d_in[5];
    const float* b3  = (const float*)d_in[6];
    float* out = (float*)d_out;

    char* ws = (char*)d_ws;
    size_t off = 0;
    auto alloc = [&](size_t bytes) -> void* {
        void* p = ws + off;
        off = (off + bytes + 255) & ~(size_t)255;
        return p;
    };
    unsigned int*   pS     = (unsigned int*)alloc((size_t)HBLOCKS * HWORDS * 4);
    unsigned int*   pD     = (unsigned int*)alloc((size_t)HBLOCKS * HWORDS * 4);
    unsigned int*   pref   = (unsigned int*)alloc((size_t)HBLOCKS * HWORDS * 4);
    float*          Y0     = (float*)alloc(SLICE2 * 2 * 4);
    float*          Y1     = (float*)alloc(SLICE2 * 2 * 4);
    unsigned short* csr    = (unsigned short*)alloc((size_t)N_NODES * CSTRIDE * 2);
    int*            deg_in = (int*)alloc((size_t)N_NODES * 4);
    float*          ns     = (float*)alloc((size_t)N_NODES * 4);
    float*          nd     = (float*)alloc((size_t)N_NODES * 4);
    float*          cc     = (float*)alloc((size_t)N_NODES * 4);
    int*            perm   = (int*)alloc((size_t)N_NODES * 4);
    int*            inv    = (int*)alloc((size_t)N_NODES * 4);
    int*            degP   = (int*)alloc((size_t)N_NODES * 4);
    float*          ccP    = (float*)alloc((size_t)N_NODES * 4);
    float*          nsP    = (float*)alloc((size_t)N_NODES * 4);
    float*          ndP    = (float*)alloc((size_t)N_NODES * 4);
    int*            dparts = (int*)alloc((size_t)P2BLOCKS * 65 * 4);
    float*          W13    = (float*)alloc((size_t)DIN * DOUT * 4);
    float*          bb     = (float*)alloc(DOUT * 4);

    const int sblk = 391 * 8;   // 3128 blocks -> 6256 pair-slots x 2 slices

    k_setup<<<SB_TOT, 256, 0, stream>>>(src, dst, pS, pD, (unsigned int*)csr,
                                        W1, b1, W3, W13, bb, Y0, Y1);
    k_hpre<<<P2BLOCKS, 256, 0, stream>>>(pS, pD, pref, deg_in, ns, nd, cc, dparts);
    k_dscatter<<<P2BLOCKS, 128, 0, stream>>>(deg_in, dparts, cc, ns, nd,
                                             perm, inv, degP, ccP, nsP, ndP);
    k_fill<<<HBLOCKS, 256, 0, stream>>>(src, dst, pref, inv, csr);

    // Y0 = ns ∘ (X @ (W1@W3)), 2-slice layout, renumbered rows
    k_gemm<<<(N_NODES + 63) / 64, 256, 0, stream>>>(X, W13, ns, inv, Y0);

    // 6 propagation passes; bias bb injected in pass 1, b3 in pass 6
    k_spmm<0><<<sblk, 256, 0, stream>>>(Y0, Y1, csr, degP, ccP, nsP, ndP, bb, b3, perm);
    k_spmm<1><<<sblk, 256, 0, stream>>>(Y1, Y0, csr, degP, ccP, nsP, ndP, bb, b3, perm);
    k_spmm<1><<<sblk, 256, 0, stream>>>(Y0, Y1, csr, degP, ccP, nsP, ndP, bb, b3, perm);
    k_spmm<1><<<sblk, 256, 0, stream>>>(Y1, Y0, csr, degP, ccP, nsP, ndP, bb, b3, perm);
    k_spmm<1><<<sblk, 256, 0, stream>>>(Y0, Y1, csr, degP, ccP, nsP, ndP, bb, b3, perm);
    k_spmm<2><<<sblk, 256, 0, stream>>>(Y1, out, csr, degP, ccP, nsP, ndP, bb, b3, perm);
}